// Round 2
// baseline (521.388 us; speedup 1.0000x reference)
//
#include <hip/hip_runtime.h>
#include <hip/hip_bf16.h>
#include <math.h>

typedef __attribute__((ext_vector_type(8))) short short8;
typedef __attribute__((ext_vector_type(4))) float f32x4;
typedef unsigned short u16;

// ---------- helpers ----------
__device__ __forceinline__ u16 f2bf(float f) {
  union { float f; unsigned u; } x; x.f = f;
  unsigned r = x.u + 0x7fffu + ((x.u >> 16) & 1u);   // RNE
  return (u16)(r >> 16);
}

// exact T5 bucket: matches floor(2*log2(n/8)) with integer arithmetic
__device__ __forceinline__ int bucket_fn(int rel) {
  int n = -rel;              // i - j
  int ret = 0;
  if (n < 0) { ret = 16; n = -n; }
  if (n < 8) return ret + n;
  int e = 31 - __clz(n);
  unsigned nn = (unsigned)n * (unsigned)n;
  int f = 2 * e + ((nn >= (1u << (2 * e + 1))) ? 1 : 0) - 6;
  int val = 8 + f;
  if (val > 15) val = 15;
  return ret + val;
}

// ---------- small kernels ----------
__global__ __launch_bounds__(256) void f2b_kernel(const float* __restrict__ in,
                                                  u16* __restrict__ out, int n) {
  int i = (blockIdx.x * 256 + threadIdx.x) * 4;
  if (i >= n) return;
  float4 v = *(const float4*)&in[i];
  out[i + 0] = f2bf(v.x); out[i + 1] = f2bf(v.y);
  out[i + 2] = f2bf(v.z); out[i + 3] = f2bf(v.w);
}

__global__ __launch_bounds__(256) void build_tab(const float* __restrict__ rel_bias,
                                                 float* __restrict__ tab) {
  int idx = blockIdx.x * 256 + threadIdx.x;     // 16*2048
  int h = idx >> 11;
  int rel = (idx & 2047) - 1024;
  tab[idx] = rel_bias[bucket_fn(rel) * 16 + h];
}

__global__ __launch_bounds__(256) void write_pb(const float* __restrict__ tab,
                                                float* __restrict__ pb) {
  const int i = blockIdx.x, h = blockIdx.y, t = threadIdx.x;
  __shared__ float tabs[2048];
  ((float4*)tabs)[t]       = ((const float4*)(tab + h * 2048))[t];
  ((float4*)tabs)[t + 256] = ((const float4*)(tab + h * 2048))[t + 256];
  __syncthreads();
  const int j = t * 4;
  float4 o;
  o.x = tabs[j + 0 - i + 1024];
  o.y = tabs[j + 1 - i + 1024];
  o.z = tabs[j + 2 - i + 1024];
  o.w = tabs[j + 3 - i + 1024];
#pragma unroll
  for (int b = 0; b < 4; b++)
    *(float4*)&pb[(((size_t)(b * 16 + h)) * 1024 + i) * 1024 + j] = o;
}

__global__ __launch_bounds__(256) void t5_ln(const float* __restrict__ x,
                                             const float* __restrict__ wgt,
                                             float eps, u16* __restrict__ out) {
  const int row = blockIdx.x, t = threadIdx.x;
  const float4 v = ((const float4*)(x + (size_t)row * 1024))[t];
  float ss = v.x * v.x + v.y * v.y + v.z * v.z + v.w * v.w;
#pragma unroll
  for (int off = 1; off < 64; off <<= 1) ss += __shfl_xor(ss, off, 64);
  __shared__ float red[4];
  if ((t & 63) == 0) red[t >> 6] = ss;
  __syncthreads();
  float tot = red[0] + red[1] + red[2] + red[3];
  float inv = 1.0f / sqrtf(tot * (1.0f / 1024.0f) + eps);
  const float4 wv = ((const float4*)wgt)[t];
  u16* o = out + (size_t)row * 1024 + t * 4;
  o[0] = f2bf(v.x * inv * wv.x);
  o[1] = f2bf(v.y * inv * wv.y);
  o[2] = f2bf(v.z * inv * wv.z);
  o[3] = f2bf(v.w * inv * wv.w);
}

__global__ __launch_bounds__(256) void transpose_v(const u16* __restrict__ v,
                                                   u16* __restrict__ vt) {
  __shared__ u16 T[64][72];
  const int bh = blockIdx.y;
  const int l0 = blockIdx.x * 64;
  const int t = threadIdx.x;
  const int sr = t >> 3, sc = (t & 7) * 8;
  const u16* vb = v + (size_t)bh * 65536;
  *(short8*)&T[sr][sc]      = *(const short8*)&vb[(size_t)(l0 + sr) * 64 + sc];
  *(short8*)&T[sr + 32][sc] = *(const short8*)&vb[(size_t)(l0 + sr + 32) * 64 + sc];
  __syncthreads();
  u16* vtb = vt + (size_t)bh * 65536;
  short8 o0, o1;
#pragma unroll
  for (int u = 0; u < 8; u++) {
    ((u16*)&o0)[u] = T[sc + u][sr];
    ((u16*)&o1)[u] = T[sc + u][sr + 32];
  }
  *(short8*)&vtb[(size_t)sr * 1024 + l0 + sc]        = o0;
  *(short8*)&vtb[(size_t)(sr + 32) * 1024 + l0 + sc] = o1;
}

// ---------- GEMM: C[M,N] = A[M,K] * B[N,K]^T  (bf16 in, f32 acc) ----------
// MODE 0: (acc+bias)*scale -> bf16 permuted [b,h,pos,dk]
// MODE 1: acc+bias+res -> f32 (attn_out)
// MODE 2: gelu(acc) -> bf16
// MODE 3: acc+res -> f32 (final out)
template<int MODE>
__global__ __launch_bounds__(256) void gemm_nt(
    const u16* __restrict__ A, const u16* __restrict__ Bw,
    int M, int N, int K,
    const float* __restrict__ bias, const float* __restrict__ res,
    float scale, float* __restrict__ outF, u16* __restrict__ outB) {
  __shared__ u16 As[128][32];
  __shared__ u16 Bs[128][32];
  const int t = threadIdx.x;
  const int w = t >> 6, lane = t & 63;
  const int wr = w >> 1, wc = w & 1;
  const int g = lane >> 4, lc = lane & 15;
  const int m0 = blockIdx.y * 128, n0 = blockIdx.x * 128;
  const int ar = t >> 2, ac = (t & 3) * 8;

  f32x4 acc[4][4] = {};

  for (int k0 = 0; k0 < K; k0 += 32) {
    __syncthreads();
    *(short8*)&As[ar][ac]      = *(const short8*)&A[(size_t)(m0 + ar) * K + k0 + ac];
    *(short8*)&As[ar + 64][ac] = *(const short8*)&A[(size_t)(m0 + ar + 64) * K + k0 + ac];
    *(short8*)&Bs[ar][ac]      = *(const short8*)&Bw[(size_t)(n0 + ar) * K + k0 + ac];
    *(short8*)&Bs[ar + 64][ac] = *(const short8*)&Bw[(size_t)(n0 + ar + 64) * K + k0 + ac];
    __syncthreads();
    short8 af[4], bf[4];
#pragma unroll
    for (int mi = 0; mi < 4; mi++) af[mi] = *(short8*)&As[wr * 64 + mi * 16 + lc][g * 8];
#pragma unroll
    for (int ni = 0; ni < 4; ni++) bf[ni] = *(short8*)&Bs[wc * 64 + ni * 16 + lc][g * 8];
#pragma unroll
    for (int mi = 0; mi < 4; mi++)
#pragma unroll
      for (int ni = 0; ni < 4; ni++)
        acc[mi][ni] = __builtin_amdgcn_mfma_f32_16x16x32_bf16(af[mi], bf[ni], acc[mi][ni], 0, 0, 0);
  }

#pragma unroll
  for (int mi = 0; mi < 4; mi++) {
#pragma unroll
    for (int ni = 0; ni < 4; ni++) {
#pragma unroll
      for (int r = 0; r < 4; r++) {
        const int row = m0 + wr * 64 + mi * 16 + g * 4 + r;
        const int col = n0 + wc * 64 + ni * 16 + lc;
        float v = acc[mi][ni][r];
        if (MODE == 0) {
          v = (v + bias[col]) * scale;
          const int b = row >> 10, pos = row & 1023, hh = col >> 6, dk = col & 63;
          outB[(((size_t)(b * 16 + hh)) * 1024 + pos) * 64 + dk] = f2bf(v);
        } else if (MODE == 1) {
          v += bias[col] + res[(size_t)row * 1024 + col];
          outF[(size_t)row * 1024 + col] = v;
        } else if (MODE == 2) {
          v = 0.5f * v * (1.0f + erff(v * 0.70710678118654752440f));
          outB[(size_t)row * (size_t)N + col] = f2bf(v);
        } else {
          v += res[(size_t)row * 1024 + col];
          outF[(size_t)row * 1024 + col] = v;
        }
      }
    }
  }
}

// ---------- flash attention: ctx + (m,l) ----------
__global__ __launch_bounds__(256) void attn_kernel(
    const u16* __restrict__ q, const u16* __restrict__ k,
    const u16* __restrict__ vt, const float* __restrict__ tab,
    u16* __restrict__ ctx, float* __restrict__ ml) {
  const int bh = blockIdx.y;
  const int h = bh & 15, b = bh >> 4;
  const int i0 = blockIdx.x * 64;
  const int t = threadIdx.x, w = t >> 6, lane = t & 63;
  const int g = lane >> 4, lc = lane & 15;
  const int sr = t >> 3, sc = (t & 7) * 8;

  __shared__ u16 Ks[64][64];
  __shared__ u16 Vts[64][64];
  __shared__ u16 P[4][16][64];
  __shared__ float tabs[128];

  const u16* qb  = q + (size_t)bh * 65536;
  const u16* kb  = k + (size_t)bh * 65536;
  const u16* vtb = vt + (size_t)bh * 65536;

  const short8 aq0 = *(const short8*)&qb[(size_t)(i0 + w * 16 + lc) * 64 + g * 8];
  const short8 aq1 = *(const short8*)&qb[(size_t)(i0 + w * 16 + lc) * 64 + 32 + g * 8];

  float m_r[4] = {-INFINITY, -INFINITY, -INFINITY, -INFINITY};
  float l_r[4] = {0.f, 0.f, 0.f, 0.f};
  f32x4 cacc[4] = {};

  for (int j0 = 0; j0 < 1024; j0 += 64) {
    __syncthreads();
    *(short8*)&Ks[sr][sc]       = *(const short8*)&kb[(size_t)(j0 + sr) * 64 + sc];
    *(short8*)&Ks[sr + 32][sc]  = *(const short8*)&kb[(size_t)(j0 + sr + 32) * 64 + sc];
    *(short8*)&Vts[sr][sc]      = *(const short8*)&vtb[(size_t)sr * 1024 + j0 + sc];
    *(short8*)&Vts[sr + 32][sc] = *(const short8*)&vtb[(size_t)(sr + 32) * 1024 + j0 + sc];
    if (t < 127) tabs[t] = tab[h * 2048 + (j0 - i0 - 63 + t) + 1024];
    __syncthreads();

    f32x4 s[4] = {};
#pragma unroll
    for (int ni = 0; ni < 4; ni++) {
      short8 b0 = *(short8*)&Ks[ni * 16 + lc][g * 8];
      short8 b1 = *(short8*)&Ks[ni * 16 + lc][32 + g * 8];
      s[ni] = __builtin_amdgcn_mfma_f32_16x16x32_bf16(aq0, b0, s[ni], 0, 0, 0);
      s[ni] = __builtin_amdgcn_mfma_f32_16x16x32_bf16(aq1, b1, s[ni], 0, 0, 0);
    }
#pragma unroll
    for (int ni = 0; ni < 4; ni++)
#pragma unroll
      for (int r = 0; r < 4; r++)
        s[ni][r] += tabs[ni * 16 + lc - w * 16 - g * 4 - r + 63];

#pragma unroll
    for (int r = 0; r < 4; r++) {
      float tm = fmaxf(fmaxf(s[0][r], s[1][r]), fmaxf(s[2][r], s[3][r]));
#pragma unroll
      for (int off = 1; off < 16; off <<= 1) tm = fmaxf(tm, __shfl_xor(tm, off, 64));
      const float mn = fmaxf(m_r[r], tm);
      const float scl = expf(m_r[r] - mn);
      float rs = 0.f;
#pragma unroll
      for (int ni = 0; ni < 4; ni++) {
        float p = expf(s[ni][r] - mn);
        s[ni][r] = p;
        rs += p;
      }
#pragma unroll
      for (int off = 1; off < 16; off <<= 1) rs += __shfl_xor(rs, off, 64);
      l_r[r] = l_r[r] * scl + rs;
      m_r[r] = mn;
#pragma unroll
      for (int d = 0; d < 4; d++) cacc[d][r] *= scl;
    }

#pragma unroll
    for (int ni = 0; ni < 4; ni++)
#pragma unroll
      for (int r = 0; r < 4; r++)
        P[w][g * 4 + r][ni * 16 + lc] = f2bf(s[ni][r]);

    short8 ap0 = *(short8*)&P[w][lc][g * 8];
    short8 ap1 = *(short8*)&P[w][lc][32 + g * 8];
#pragma unroll
    for (int d = 0; d < 4; d++) {
      short8 bv0 = *(short8*)&Vts[d * 16 + lc][g * 8];
      short8 bv1 = *(short8*)&Vts[d * 16 + lc][32 + g * 8];
      cacc[d] = __builtin_amdgcn_mfma_f32_16x16x32_bf16(ap0, bv0, cacc[d], 0, 0, 0);
      cacc[d] = __builtin_amdgcn_mfma_f32_16x16x32_bf16(ap1, bv1, cacc[d], 0, 0, 0);
    }
  }

  float inv[4];
#pragma unroll
  for (int r = 0; r < 4; r++) inv[r] = 1.0f / l_r[r];
#pragma unroll
  for (int d = 0; d < 4; d++)
#pragma unroll
    for (int r = 0; r < 4; r++) {
      const int pos = i0 + w * 16 + g * 4 + r;
      ctx[((size_t)b * 1024 + pos) * 1024 + h * 64 + d * 16 + lc] = f2bf(cacc[d][r] * inv[r]);
    }
  if (lc == 0) {
#pragma unroll
    for (int r = 0; r < 4; r++) {
      const int i = i0 + w * 16 + g * 4 + r;
      ml[(size_t)bh * 1024 + i] = m_r[r];
      ml[65536 + (size_t)bh * 1024 + i] = l_r[r];
    }
  }
}

// ---------- attn_sum: recompute scores, sum over heads ----------
__global__ __launch_bounds__(256) void attn_sum_kernel(
    const u16* __restrict__ q, const u16* __restrict__ k,
    const float* __restrict__ tab, const float* __restrict__ ml,
    float* __restrict__ asum) {
  const int b = blockIdx.z;
  const int i0 = blockIdx.y * 64;
  const int j0 = blockIdx.x * 64;
  const int t = threadIdx.x, w = t >> 6, lane = t & 63;
  const int g = lane >> 4, lc = lane & 15;
  const int sr = t >> 3, sc = (t & 7) * 8;
  __shared__ u16 Ks[64][64];
  __shared__ float tabs[128];

  f32x4 acc[4] = {};

  for (int h = 0; h < 16; h++) {
    const int bh = b * 16 + h;
    __syncthreads();
    const u16* kb = k + (size_t)bh * 65536;
    *(short8*)&Ks[sr][sc]      = *(const short8*)&kb[(size_t)(j0 + sr) * 64 + sc];
    *(short8*)&Ks[sr + 32][sc] = *(const short8*)&kb[(size_t)(j0 + sr + 32) * 64 + sc];
    if (t < 127) tabs[t] = tab[h * 2048 + (j0 - i0 - 63 + t) + 1024];
    __syncthreads();
    const u16* qb = q + (size_t)bh * 65536;
    short8 aq0 = *(const short8*)&qb[(size_t)(i0 + w * 16 + lc) * 64 + g * 8];
    short8 aq1 = *(const short8*)&qb[(size_t)(i0 + w * 16 + lc) * 64 + 32 + g * 8];
    f32x4 s[4] = {};
#pragma unroll
    for (int ni = 0; ni < 4; ni++) {
      short8 b0 = *(short8*)&Ks[ni * 16 + lc][g * 8];
      short8 b1 = *(short8*)&Ks[ni * 16 + lc][32 + g * 8];
      s[ni] = __builtin_amdgcn_mfma_f32_16x16x32_bf16(aq0, b0, s[ni], 0, 0, 0);
      s[ni] = __builtin_amdgcn_mfma_f32_16x16x32_bf16(aq1, b1, s[ni], 0, 0, 0);
    }
    float mm[4], li[4];
#pragma unroll
    for (int r = 0; r < 4; r++) {
      const int i = i0 + w * 16 + g * 4 + r;
      mm[r] = ml[(size_t)bh * 1024 + i];
      li[r] = 1.0f / ml[65536 + (size_t)bh * 1024 + i];
    }
#pragma unroll
    for (int ni = 0; ni < 4; ni++)
#pragma unroll
      for (int r = 0; r < 4; r++) {
        float sv = s[ni][r] + tabs[ni * 16 + lc - w * 16 - g * 4 - r + 63];
        acc[ni][r] += expf(sv - mm[r]) * li[r];
      }
  }
#pragma unroll
  for (int ni = 0; ni < 4; ni++)
#pragma unroll
    for (int r = 0; r < 4; r++) {
      const int i = i0 + w * 16 + g * 4 + r;
      asum[((size_t)b * 1024 + i) * 1024 + j0 + ni * 16 + lc] = acc[ni][r];
    }
}

// ---------- launch ----------
extern "C" void kernel_launch(void* const* d_in, const int* in_sizes, int n_in,
                              void* d_out, int out_size, void* d_ws, size_t ws_size,
                              hipStream_t stream) {
  const float* src      = (const float*)d_in[0];
  const float* ln1_w    = (const float*)d_in[2];
  const float* wq       = (const float*)d_in[3];
  const float* bq       = (const float*)d_in[4];
  const float* wk       = (const float*)d_in[5];
  const float* bk       = (const float*)d_in[6];
  const float* wv       = (const float*)d_in[7];
  const float* bv       = (const float*)d_in[8];
  const float* fc_w     = (const float*)d_in[9];
  const float* fc_b     = (const float*)d_in[10];
  const float* rel_bias = (const float*)d_in[11];
  const float* ln2_w    = (const float*)d_in[12];
  const float* wi       = (const float*)d_in[13];
  const float* wo       = (const float*)d_in[14];

  const size_t MB = 1u << 20;
  char* ws = (char*)d_ws;
  u16* wq_b   = (u16*)(ws + 0 * MB);
  u16* wk_b   = (u16*)(ws + 2 * MB);
  u16* wv_b   = (u16*)(ws + 4 * MB);
  u16* fcw_b  = (u16*)(ws + 6 * MB);
  u16* wi_b   = (u16*)(ws + 8 * MB);
  u16* wo_b   = (u16*)(ws + 16 * MB);
  u16* proj_b = (u16*)(ws + 24 * MB);   // reused as nx
  u16* q_b    = (u16*)(ws + 32 * MB);
  u16* k_b    = (u16*)(ws + 40 * MB);
  u16* v_b    = (u16*)(ws + 48 * MB);
  u16* vt_b   = (u16*)(ws + 56 * MB);
  u16* h_b    = (u16*)(ws + 32 * MB);   // aliases q/k/v/vt (dead by then)
  u16* ctx_b  = (u16*)(ws + 64 * MB);
  float* attn_out = (float*)(ws + 72 * MB);
  float* ml   = (float*)(ws + 88 * MB);
  float* tab  = (float*)(ws + 88 * MB + 512 * 1024);

  float* outF = (float*)d_out;
  float* asum = outF + 4194304;
  float* pb   = outF + 8388608;

  f2b_kernel<<<1024, 256, 0, stream>>>(wq, wq_b, 1048576);
  f2b_kernel<<<1024, 256, 0, stream>>>(wk, wk_b, 1048576);
  f2b_kernel<<<1024, 256, 0, stream>>>(wv, wv_b, 1048576);
  f2b_kernel<<<1024, 256, 0, stream>>>(fc_w, fcw_b, 1048576);
  f2b_kernel<<<4096, 256, 0, stream>>>(wi, wi_b, 4194304);
  f2b_kernel<<<4096, 256, 0, stream>>>(wo, wo_b, 4194304);

  build_tab<<<128, 256, 0, stream>>>(rel_bias, tab);
  write_pb<<<dim3(1024, 16), 256, 0, stream>>>(tab, pb);

  t5_ln<<<4096, 256, 0, stream>>>(src, ln1_w, 1e-12f, proj_b);

  gemm_nt<0><<<dim3(8, 32), 256, 0, stream>>>(proj_b, wq_b, 4096, 1024, 1024, bq, nullptr, 0.125f, nullptr, q_b);
  gemm_nt<0><<<dim3(8, 32), 256, 0, stream>>>(proj_b, wk_b, 4096, 1024, 1024, bk, nullptr, 1.0f, nullptr, k_b);
  gemm_nt<0><<<dim3(8, 32), 256, 0, stream>>>(proj_b, wv_b, 4096, 1024, 1024, bv, nullptr, 1.0f, nullptr, v_b);

  transpose_v<<<dim3(16, 64), 256, 0, stream>>>(v_b, vt_b);
  attn_kernel<<<dim3(16, 64), 256, 0, stream>>>(q_b, k_b, vt_b, tab, ctx_b, ml);
  attn_sum_kernel<<<dim3(16, 16, 4), 256, 0, stream>>>(q_b, k_b, tab, ml, asum);

  gemm_nt<1><<<dim3(8, 32), 256, 0, stream>>>(ctx_b, fcw_b, 4096, 1024, 1024, fc_b, src, 1.0f, attn_out, nullptr);

  t5_ln<<<4096, 256, 0, stream>>>(attn_out, ln2_w, 1e-6f, proj_b);

  gemm_nt<2><<<dim3(32, 32), 256, 0, stream>>>(proj_b, wi_b, 4096, 4096, 1024, nullptr, nullptr, 1.0f, nullptr, h_b);
  gemm_nt<3><<<dim3(8, 32), 256, 0, stream>>>(h_b, wo_b, 4096, 1024, 4096, nullptr, attn_out, 1.0f, outF, nullptr);
}